// Round 10
// baseline (633.238 us; speedup 1.0000x reference)
//
#include <hip/hip_runtime.h>
#include <math.h>

#define BATCH 4
#define A_TOTAL 159882
#define K_TOT 4507
#define N_WORDS 71
#define POST_N 1000

// ---- workspace offsets (bytes), all 256-aligned ----
#define OFF_SEL      0u          // int[BATCH*K_TOT]
#define OFF_SKEY     72192u      // u64[BATCH*K_TOT]
#define OFF_BOXES    216576u     // float4[BATCH*K_TOT]
#define OFF_SCORE    505088u     // float[BATCH*K_TOT]
#define OFF_MAXC     577280u     // float[BATCH]
#define OFF_BOXESS   577536u     // float4[BATCH*K_TOT] (sorted)
#define OFF_NBS      866048u     // float4[BATCH*K_TOT] (sorted, level-offset)
#define OFF_SCORES   1154560u    // float[BATCH*K_TOT] (sorted)
#define OFF_SUPINIT  1226752u    // u64[BATCH*N_WORDS]
#define OFF_MASK     1229056u    // u64[BATCH*K_TOT*N_WORDS]  (~10.2 MB)

__device__ const int d_LVL_N[5]   = {120000, 30000, 7500, 1875, 507};
__device__ const int d_LVL_OFF[5] = {0, 120000, 150000, 157500, 159375};
__device__ const int d_LVL_K[5]   = {1000, 1000, 1000, 1000, 507};
__device__ const int d_CAT_OFF[5] = {0, 1000, 2000, 3000, 4000};

// _rn intrinsics: block -ffp-contract=fast fusion so mul/add round separately (match XLA)
__device__ __forceinline__ float fadd_(float a, float b) { return __fadd_rn(a, b); }
__device__ __forceinline__ float fsub_(float a, float b) { return __fadd_rn(a, -b); }
__device__ __forceinline__ float fmul_(float a, float b) { return __fmul_rn(a, b); }

__device__ __forceinline__ unsigned flipf(float f) {
  unsigned u = __float_as_uint(f);
  return (u & 0x80000000u) ? ~u : (u | 0x80000000u);
}

__device__ __forceinline__ unsigned long long readlane64(unsigned long long v, int l) {
  unsigned lo = (unsigned)__builtin_amdgcn_readlane((int)(unsigned)(v & 0xffffffffull), l);
  unsigned hi = (unsigned)__builtin_amdgcn_readlane((int)(unsigned)(v >> 32), l);
  return ((unsigned long long)hi << 32) | (unsigned long long)lo;
}

// suffix-sum over hist[0..2048) then find bucket B with suffix[B] >= kcur > suffix[B+1]
__device__ void suffix_and_find(unsigned* hist, unsigned kcur,
                                unsigned* s_bucket, unsigned* s_knew, int tid) {
  for (int off = 1; off < 2048; off <<= 1) {
    unsigned v0 = hist[tid] + ((tid + off) < 2048 ? hist[tid + off] : 0u);
    unsigned v1 = hist[tid + 1024] + ((tid + 1024 + off) < 2048 ? hist[tid + 1024 + off] : 0u);
    __syncthreads();
    hist[tid] = v0; hist[tid + 1024] = v1;
    __syncthreads();
  }
  for (int q = 0; q < 2; ++q) {
    int idx = tid + q * 1024;
    unsigned s0 = hist[idx];
    unsigned s1 = (idx + 1 < 2048) ? hist[idx + 1] : 0u;
    if (s0 >= kcur && s1 < kcur) { *s_bucket = (unsigned)idx; *s_knew = kcur - s1; }
  }
  __syncthreads();
}

// ---- Kernel A: per-(batch,level) exact top-k (jax.lax.top_k semantics) ----
__global__ __launch_bounds__(1024) void topk_kernel(const float* __restrict__ obj,
                                                    int* __restrict__ selAnchor) {
  __shared__ unsigned hist[2048];
  __shared__ unsigned long long buf[2048];
  __shared__ unsigned s_bucket, s_knew, s_cnt;
  const int tid = threadIdx.x;
  const int bid = blockIdx.x;
  const int b = bid / 5, l = bid % 5;
  const int n = d_LVL_N[l];
  const int aoff = d_LVL_OFF[l];
  const unsigned kk = (unsigned)d_LVL_K[l];
  const float* src = obj + (size_t)b * A_TOTAL + aoff;

  // round 1: top 11 bits
  hist[tid] = 0; hist[tid + 1024] = 0;
  __syncthreads();
  for (int i = tid; i < n; i += 1024) atomicAdd(&hist[flipf(src[i]) >> 21], 1u);
  __syncthreads();
  suffix_and_find(hist, kk, &s_bucket, &s_knew, tid);
  unsigned B1 = s_bucket, k2 = s_knew;
  __syncthreads();

  // round 2: next 11 bits
  hist[tid] = 0; hist[tid + 1024] = 0;
  __syncthreads();
  for (int i = tid; i < n; i += 1024) {
    unsigned u = flipf(src[i]);
    if ((u >> 21) == B1) atomicAdd(&hist[(u >> 10) & 2047u], 1u);
  }
  __syncthreads();
  suffix_and_find(hist, k2, &s_bucket, &s_knew, tid);
  unsigned B2 = s_bucket, k3 = s_knew;
  __syncthreads();

  // round 3: last 10 bits
  hist[tid] = 0; hist[tid + 1024] = 0;
  __syncthreads();
  unsigned pfx = (B1 << 11) | B2;
  for (int i = tid; i < n; i += 1024) {
    unsigned u = flipf(src[i]);
    if ((u >> 10) == pfx) atomicAdd(&hist[u & 1023u], 1u);
  }
  __syncthreads();
  suffix_and_find(hist, k3, &s_bucket, &s_knew, tid);
  unsigned T = (pfx << 10) | s_bucket;

  // compact all u >= T, then bitonic sort desc by (value, ~idx)
  if (tid == 0) s_cnt = 0;
  __syncthreads();
  for (int i = tid; i < n; i += 1024) {
    unsigned u = flipf(src[i]);
    if (u >= T) {
      unsigned p = atomicAdd(&s_cnt, 1u);
      if (p < 2048u) buf[p] = ((unsigned long long)u << 32) | (unsigned long long)(~(unsigned)i);
    }
  }
  __syncthreads();
  unsigned cnt = s_cnt; if (cnt > 2048u) cnt = 2048u;
  for (int i = tid; i < 2048; i += 1024) if ((unsigned)i >= cnt) buf[i] = 0ull;
  for (unsigned kq = 2; kq <= 2048; kq <<= 1) {
    for (unsigned j = kq >> 1; j; j >>= 1) {
      __syncthreads();
      unsigned t = (unsigned)tid;
      unsigned i0 = ((t & ~(j - 1)) << 1) | (t & (j - 1));
      unsigned i1 = i0 | j;
      unsigned long long a = buf[i0], c = buf[i1];
      bool up = ((i0 & kq) == 0);
      if (up ? (a < c) : (a > c)) { buf[i0] = c; buf[i1] = a; }
    }
  }
  __syncthreads();
  if ((unsigned)tid < kk) {
    unsigned long long key = buf[tid];
    unsigned lidx = ~(unsigned)(key & 0xffffffffull);
    selAnchor[b * K_TOT + d_CAT_OFF[l] + tid] = aoff + (int)lidx;
  }
}

// ---- Kernel B: decode + clip + valid + sigmoid + sort key + per-image max coord ----
__global__ __launch_bounds__(512) void decode_kernel(
    const float* __restrict__ obj, const float* __restrict__ deltas,
    const float* __restrict__ anchors, const int* __restrict__ selAnchor,
    unsigned long long* __restrict__ skey, float4* __restrict__ boxes,
    float* __restrict__ score, float* __restrict__ maxc) {
  __shared__ float red[512];
  const int b = blockIdx.x;
  const int tid = threadIdx.x;
  float mymax = 0.0f;  // clipped coords >= 0
  for (int pos = tid; pos < K_TOT; pos += 512) {
    int a = selAnchor[b * K_TOT + pos];
    float4 an = ((const float4*)anchors)[a];
    float4 dl = ((const float4*)deltas)[(size_t)b * A_TOTAL + a];
    float o = obj[(size_t)b * A_TOTAL + a];
    float wa = fsub_(an.z, an.x), ha = fsub_(an.w, an.y);
    float cxa = fadd_(an.x, fmul_(0.5f, wa));
    float cya = fadd_(an.y, fmul_(0.5f, ha));
    const float CLIP = (float)4.135166556742356;  // log(1000/16)
    float dw = fminf(dl.z, CLIP), dh = fminf(dl.w, CLIP);
    float cx = fadd_(fmul_(dl.x, wa), cxa);
    float cy = fadd_(fmul_(dl.y, ha), cya);
    float w = fmul_((float)exp((double)dw), wa);
    float h = fmul_((float)exp((double)dh), ha);
    float x1 = fsub_(cx, fmul_(0.5f, w));
    float y1 = fsub_(cy, fmul_(0.5f, h));
    float x2 = fadd_(cx, fmul_(0.5f, w));
    float y2 = fadd_(cy, fmul_(0.5f, h));
    x1 = fminf(fmaxf(x1, 0.f), 800.f);
    y1 = fminf(fmaxf(y1, 0.f), 800.f);
    x2 = fminf(fmaxf(x2, 0.f), 800.f);
    y2 = fminf(fmaxf(y2, 0.f), 800.f);
    bool valid = (fsub_(x2, x1) >= 0.001f) && (fsub_(y2, y1) >= 0.001f);
    float s = (float)(1.0 / (1.0 + exp(-(double)o)));
    boxes[b * K_TOT + pos] = make_float4(x1, y1, x2, y2);
    score[b * K_TOT + pos] = s;
    float sm = valid ? s : -INFINITY;
    skey[b * K_TOT + pos] =
        ((unsigned long long)flipf(sm) << 32) | (unsigned long long)(~(unsigned)pos);
    mymax = fmaxf(mymax, fmaxf(fmaxf(x1, y1), fmaxf(x2, y2)));
  }
  red[tid] = mymax;
  __syncthreads();
  for (int s2 = 256; s2 > 0; s2 >>= 1) {
    if (tid < s2) red[tid] = fmaxf(red[tid], red[tid + s2]);
    __syncthreads();
  }
  if (tid == 0) maxc[b] = red[0];
}

// ---- Kernel S: stable sort by (score desc, pos asc); emit sorted arrays + valid bitmask ----
__global__ __launch_bounds__(1024) void sort_kernel(
    const unsigned long long* __restrict__ skey, const float4* __restrict__ boxes,
    const float* __restrict__ score, const float* __restrict__ maxc,
    float4* __restrict__ boxesS, float4* __restrict__ nbS,
    float* __restrict__ scoreS, unsigned long long* __restrict__ supInit) {
  __shared__ unsigned long long keys[8192];
  const int b = blockIdx.x;
  const int tid = threadIdx.x;
  for (int t = tid; t < 8192; t += 1024)
    keys[t] = (t < K_TOT) ? skey[b * K_TOT + t] : 0ull;
  for (unsigned kq = 2; kq <= 8192; kq <<= 1) {
    for (unsigned j = kq >> 1; j; j >>= 1) {
      __syncthreads();
      for (unsigned t = (unsigned)tid; t < 4096; t += 1024) {
        unsigned i0 = ((t & ~(j - 1)) << 1) | (t & (j - 1));
        unsigned i1 = i0 | j;
        unsigned long long a = keys[i0], c = keys[i1];
        bool up = ((i0 & kq) == 0);
        if (up ? (a < c) : (a > c)) { keys[i0] = c; keys[i1] = a; }
      }
    }
  }
  __syncthreads();
  float mc1 = fadd_(maxc[b], 1.0f);
  for (int t = tid; t < 8192; t += 1024) {
    unsigned long long key = keys[t];
    bool inr = t < K_TOT;
    unsigned pos = ~(unsigned)(key & 0xffffffffull);
    bool valid = inr && ((unsigned)(key >> 32) != 0x007FFFFFu);  // flip(-inf)
    if (inr) {
      float4 bx = boxes[b * K_TOT + pos];
      boxesS[b * K_TOT + t] = bx;
      int lvl = (int)(pos / 1000u);
      float offv = fmul_((float)lvl, mc1);
      nbS[b * K_TOT + t] = make_float4(fadd_(bx.x, offv), fadd_(bx.y, offv),
                                       fadd_(bx.z, offv), fadd_(bx.w, offv));
      scoreS[b * K_TOT + t] = score[b * K_TOT + pos];
    }
    unsigned long long bal = __ballot(valid);
    if (t < N_WORDS * 64 && (threadIdx.x & 63) == 0)
      supInit[b * N_WORDS + (t >> 6)] = ~bal;
  }
}

// ---- Kernel C: suppression bitmask (upper-triangular 64x64 tiles) ----
__global__ __launch_bounds__(64) void mask_kernel(const float4* __restrict__ nbS,
                                                  unsigned long long* __restrict__ mask) {
  const int b = blockIdx.y;
  int rem = blockIdx.x;
  int ib = 0;
  while (rem >= N_WORDS - ib) { rem -= (N_WORDS - ib); ++ib; }
  const int jb = ib + rem;
  __shared__ float4 jbox[64];
  __shared__ float jarea[64];
  const int lane = threadIdx.x;
  const int j0 = jb * 64;
  {
    int jj = j0 + lane;
    float4 bj = (jj < K_TOT) ? nbS[(size_t)b * K_TOT + jj]
                             : make_float4(-1e30f, -1e30f, -1e30f, -1e30f);
    jbox[lane] = bj;
    jarea[lane] = fmul_(fsub_(bj.z, bj.x), fsub_(bj.w, bj.y));
  }
  __syncthreads();
  const int i = ib * 64 + lane;
  if (i >= K_TOT) return;
  float4 bi = nbS[(size_t)b * K_TOT + i];
  float ai = fmul_(fsub_(bi.z, bi.x), fsub_(bi.w, bi.y));
  unsigned long long bits = 0ull;
  int jmax = K_TOT - j0; if (jmax > 64) jmax = 64;
  for (int q = 0; q < jmax; ++q) {
    int j = j0 + q;
    if (j <= i) continue;
    float4 bj = jbox[q];
    float ltx = fmaxf(bi.x, bj.x), lty = fmaxf(bi.y, bj.y);
    float rbx = fminf(bi.z, bj.z), rby = fminf(bi.w, bj.w);
    float wx = fmaxf(fsub_(rbx, ltx), 0.f), wy = fmaxf(fsub_(rby, lty), 0.f);
    float inter = fmul_(wx, wy);
    float uni = fsub_(fadd_(ai, jarea[q]), inter);
    float iou = inter / uni;  // IEEE div; 0/0=NaN -> not > thresh (matches ref)
    if (iou > 0.7f) bits |= (1ull << q);
  }
  mask[((size_t)b * K_TOT + i) * N_WORDS + jb] = bits;
}

// ---- Kernel D: sequential greedy-NMS scan, one wave per image ----
// R2: emit decoupled. R3: branch-free 16-row OR batches (423->165us).
// R4: named-register batches: NO-OP -- pre-RA scheduler sank loads to
//     consumers (VGPR pinned 32, ~5 latencies/word).
// R5/R7: global_load_lds DMA: clustered loads but serial LDS read-back
//     (runtime-count chain) -> 181us. Net loss.
// R9 two-armed A/B (infra ate 3 rounds; pack both candidate fixes):
//   V=0 (TRUSTED, runs last, owns final out): plain loads +
//       sched_barrier(0) between load block and OR block. Loads have no
//       consumer in their region -> cluster; live ranges cross barrier ->
//       RA must keep 64 result VGPRs. Confirm via VGPR_Count >= ~96.
//   V=1 (EXPERIMENTAL, runs first, output overwritten): volatile inline-asm
//       global_load_dwordx2 per row-word + explicit vmcnt(0) + rule-18
//       sched_barrier(0). Volatile ordering guarantees clustering unless
//       SIInsertWaitcnts drains per-asm (then it shows ~300us+ = diagnostic).
template <int V>
__global__ __launch_bounds__(64, 1) void scan_tpl(
    const unsigned long long* __restrict__ mask,
    const unsigned long long* __restrict__ supInit,
    const float4* __restrict__ boxesS, const float* __restrict__ scoreS,
    float* __restrict__ out) {
  __shared__ unsigned short keptIdx[POST_N];
  const int b = blockIdx.x;
  const int lane = threadIdx.x;
  const unsigned long long* m = mask + (size_t)b * K_TOT * N_WORDS;
  unsigned long long supA = supInit[b * N_WORDS + lane];                       // word = lane
  unsigned long long supB = (lane < N_WORDS - 64) ? supInit[b * N_WORDS + 64 + lane] : ~0ull;
  float4* ob = (float4*)(out + (size_t)b * POST_N * 4);
  float* os = out + 4 * POST_N * 4 + (size_t)b * POST_N;
  const int lane2 = (lane + 64 < N_WORDS) ? (lane + 64) : lane;  // clamped 2nd column
  int c = 0;
  unsigned long long rw_cur = (lane < K_TOT) ? m[(size_t)lane * N_WORDS] : 0ull;
  for (int w = 0; w < N_WORDS; ++w) {
    // prefetch next group's diagonal word
    unsigned long long rw_next = 0ull;
    if (w + 1 < N_WORDS) {
      int i1 = (w + 1) * 64 + lane;
      if (i1 < K_TOT) rw_next = m[(size_t)i1 * N_WORDS + (w + 1)];
    }
    unsigned long long v = (w < 64) ? supA : supB;
    int srcl = (w < 64) ? w : (w - 64);
    unsigned long long scur = readlane64(v, srcl);
    unsigned long long avail = ~scur;
    unsigned long long keptm = 0ull;
    while (avail) {
      int t = __builtin_ctzll(avail);
      keptm |= (1ull << t);
      unsigned long long rw = readlane64(rw_cur, t);  // row's word w: same-word suppression
      avail &= ~(rw | (1ull << t));
    }
    // record kept indices in LDS (no global memory on the serial path)
    unsigned long long km = keptm;
    while (km != 0ull && c < POST_N) {
      int t = __builtin_ctzll(km); km &= km - 1ull;
      if (lane == 0) keptIdx[c] = (unsigned short)(w * 64 + t);
      ++c;
    }
    if (c >= POST_N) break;
    if (w + 1 >= N_WORDS) break;
    // OR kept rows into distributed suppression state: branch-free extract
    // -> 32 clustered loads -> fence -> masked OR-reduce.
    km = keptm;
    while (km != 0ull) {
      int ts[16];
      unsigned long long vm[16];
#pragma unroll
      for (int q = 0; q < 16; ++q) {
        unsigned long long kms = km ? km : 1ull;       // cndmask, no branch
        ts[q] = __builtin_ctzll(kms);
        vm[q] = km ? ~0ull : 0ull;
        km &= km - 1ull;
      }
      unsigned long long dA[16], dB[16];
      if constexpr (V == 1) {
#pragma unroll
        for (int q = 0; q < 16; ++q) {
          const unsigned long long* rp = m + (size_t)(w * 64 + ts[q]) * N_WORDS;
          asm volatile("global_load_dwordx2 %0, %1, off" : "=&v"(dA[q]) : "v"(rp + lane));
          asm volatile("global_load_dwordx2 %0, %1, off" : "=&v"(dB[q]) : "v"(rp + lane2));
        }
        asm volatile("s_waitcnt vmcnt(0)" ::: "memory");
        __builtin_amdgcn_sched_barrier(0);  // rule 18: fence reg-only consumers
      } else {
#pragma unroll
        for (int q = 0; q < 16; ++q) {
          const unsigned long long* row = m + (size_t)(w * 64 + ts[q]) * N_WORDS;
          dA[q] = row[lane];
          dB[q] = row[lane2];
        }
        // fence: no OR may be scheduled before this point -> loads cluster
        // above with live ranges crossing the barrier.
        __builtin_amdgcn_sched_barrier(0);
      }
      unsigned long long acc0 = 0ull, acc1 = 0ull;
#pragma unroll
      for (int q = 0; q < 16; ++q) {
        acc0 |= dA[q] & vm[q];
        acc1 |= dB[q] & vm[q];
      }
      supA |= acc0; supB |= acc1;
    }
    rw_cur = rw_next;
  }
  __syncthreads();  // make lane-0's LDS writes visible to all lanes
  // parallel gather+store of the kept boxes (64 lanes, independent loads)
  for (int t2 = lane; t2 < c; t2 += 64) {
    int i = keptIdx[t2];
    ob[t2] = boxesS[(size_t)b * K_TOT + i];
    os[t2] = scoreS[(size_t)b * K_TOT + i];
  }
  // zero-pad remaining output slots (out is poisoned each launch)
  for (int t2 = c + lane; t2 < POST_N; t2 += 64) {
    ob[t2] = make_float4(0.f, 0.f, 0.f, 0.f);
    os[t2] = 0.f;
  }
}

extern "C" void kernel_launch(void* const* d_in, const int* in_sizes, int n_in,
                              void* d_out, int out_size, void* d_ws, size_t ws_size,
                              hipStream_t stream) {
  const float* obj = (const float*)d_in[0];
  const float* deltas = (const float*)d_in[1];
  const float* anchors = (const float*)d_in[2];
  float* out = (float*)d_out;
  char* ws = (char*)d_ws;

  int* selAnchor = (int*)(ws + OFF_SEL);
  unsigned long long* skey = (unsigned long long*)(ws + OFF_SKEY);
  float4* boxes = (float4*)(ws + OFF_BOXES);
  float* score = (float*)(ws + OFF_SCORE);
  float* maxc = (float*)(ws + OFF_MAXC);
  float4* boxesS = (float4*)(ws + OFF_BOXESS);
  float4* nbS = (float4*)(ws + OFF_NBS);
  float* scoreS = (float*)(ws + OFF_SCORES);
  unsigned long long* supInit = (unsigned long long*)(ws + OFF_SUPINIT);
  unsigned long long* mask = (unsigned long long*)(ws + OFF_MASK);

  hipLaunchKernelGGL(topk_kernel, dim3(BATCH * 5), dim3(1024), 0, stream, obj, selAnchor);
  hipLaunchKernelGGL(decode_kernel, dim3(BATCH), dim3(512), 0, stream,
                     obj, deltas, anchors, selAnchor, skey, boxes, score, maxc);
  hipLaunchKernelGGL(sort_kernel, dim3(BATCH), dim3(1024), 0, stream,
                     skey, boxes, score, maxc, boxesS, nbS, scoreS, supInit);
  hipLaunchKernelGGL(mask_kernel, dim3(N_WORDS * (N_WORDS + 1) / 2, BATCH), dim3(64), 0, stream,
                     nbS, mask);
  // A/B: experimental asm variant first (its out is overwritten), trusted
  // sched_barrier variant last (owns the verified output).
  hipLaunchKernelGGL((scan_tpl<1>), dim3(BATCH), dim3(64), 0, stream,
                     mask, supInit, boxesS, scoreS, out);
  hipLaunchKernelGGL((scan_tpl<0>), dim3(BATCH), dim3(64), 0, stream,
                     mask, supInit, boxesS, scoreS, out);
}

// Round 12
// 423.822 us; speedup vs baseline: 1.4941x; 1.4941x over previous
//
#include <hip/hip_runtime.h>
#include <math.h>

#define BATCH 4
#define A_TOTAL 159882
#define K_TOT 4507
#define N_WORDS 71
#define POST_N 1000

// ---- workspace offsets (bytes), all 256-aligned ----
#define OFF_SEL      0u          // int[BATCH*K_TOT]
#define OFF_SKEY     72192u      // u64[BATCH*K_TOT]
#define OFF_BOXES    216576u     // float4[BATCH*K_TOT]
#define OFF_SCORE    505088u     // float[BATCH*K_TOT]
#define OFF_MAXC     577280u     // float[BATCH]
#define OFF_BOXESS   577536u     // float4[BATCH*K_TOT] (sorted)
#define OFF_NBS      866048u     // float4[BATCH*K_TOT] (sorted, level-offset)
#define OFF_SCORES   1154560u    // float[BATCH*K_TOT] (sorted)
#define OFF_SUPINIT  1226752u    // u64[BATCH*N_WORDS]
#define OFF_MASK     1229056u    // u64[BATCH*K_TOT*N_WORDS]  (~10.2 MB)

__device__ const int d_LVL_N[5]   = {120000, 30000, 7500, 1875, 507};
__device__ const int d_LVL_OFF[5] = {0, 120000, 150000, 157500, 159375};
__device__ const int d_LVL_K[5]   = {1000, 1000, 1000, 1000, 507};
__device__ const int d_CAT_OFF[5] = {0, 1000, 2000, 3000, 4000};

// _rn intrinsics: block -ffp-contract=fast fusion so mul/add round separately (match XLA)
__device__ __forceinline__ float fadd_(float a, float b) { return __fadd_rn(a, b); }
__device__ __forceinline__ float fsub_(float a, float b) { return __fadd_rn(a, -b); }
__device__ __forceinline__ float fmul_(float a, float b) { return __fmul_rn(a, b); }

__device__ __forceinline__ unsigned flipf(float f) {
  unsigned u = __float_as_uint(f);
  return (u & 0x80000000u) ? ~u : (u | 0x80000000u);
}

__device__ __forceinline__ unsigned long long readlane64(unsigned long long v, int l) {
  unsigned lo = (unsigned)__builtin_amdgcn_readlane((int)(unsigned)(v & 0xffffffffull), l);
  unsigned hi = (unsigned)__builtin_amdgcn_readlane((int)(unsigned)(v >> 32), l);
  return ((unsigned long long)hi << 32) | (unsigned long long)lo;
}

__device__ __forceinline__ unsigned long long shflxor64(unsigned long long v, int msk) {
  unsigned lo = __shfl_xor((unsigned)(v & 0xffffffffull), msk, 64);
  unsigned hi = __shfl_xor((unsigned)(v >> 32), msk, 64);
  return ((unsigned long long)hi << 32) | (unsigned long long)lo;
}

// suffix-sum over hist[0..2048) then find bucket B with suffix[B] >= kcur > suffix[B+1]
__device__ void suffix_and_find(unsigned* hist, unsigned kcur,
                                unsigned* s_bucket, unsigned* s_knew, int tid) {
  for (int off = 1; off < 2048; off <<= 1) {
    unsigned v0 = hist[tid] + ((tid + off) < 2048 ? hist[tid + off] : 0u);
    unsigned v1 = hist[tid + 1024] + ((tid + 1024 + off) < 2048 ? hist[tid + 1024 + off] : 0u);
    __syncthreads();
    hist[tid] = v0; hist[tid + 1024] = v1;
    __syncthreads();
  }
  for (int q = 0; q < 2; ++q) {
    int idx = tid + q * 1024;
    unsigned s0 = hist[idx];
    unsigned s1 = (idx + 1 < 2048) ? hist[idx + 1] : 0u;
    if (s0 >= kcur && s1 < kcur) { *s_bucket = (unsigned)idx; *s_knew = kcur - s1; }
  }
  __syncthreads();
}

// ---- Kernel A: per-(batch,level) exact top-k (jax.lax.top_k semantics) ----
__global__ __launch_bounds__(1024) void topk_kernel(const float* __restrict__ obj,
                                                    int* __restrict__ selAnchor) {
  __shared__ unsigned hist[2048];
  __shared__ unsigned long long buf[2048];
  __shared__ unsigned s_bucket, s_knew, s_cnt;
  const int tid = threadIdx.x;
  const int bid = blockIdx.x;
  const int b = bid / 5, l = bid % 5;
  const int n = d_LVL_N[l];
  const int aoff = d_LVL_OFF[l];
  const unsigned kk = (unsigned)d_LVL_K[l];
  const float* src = obj + (size_t)b * A_TOTAL + aoff;

  // round 1: top 11 bits
  hist[tid] = 0; hist[tid + 1024] = 0;
  __syncthreads();
  for (int i = tid; i < n; i += 1024) atomicAdd(&hist[flipf(src[i]) >> 21], 1u);
  __syncthreads();
  suffix_and_find(hist, kk, &s_bucket, &s_knew, tid);
  unsigned B1 = s_bucket, k2 = s_knew;
  __syncthreads();

  // round 2: next 11 bits
  hist[tid] = 0; hist[tid + 1024] = 0;
  __syncthreads();
  for (int i = tid; i < n; i += 1024) {
    unsigned u = flipf(src[i]);
    if ((u >> 21) == B1) atomicAdd(&hist[(u >> 10) & 2047u], 1u);
  }
  __syncthreads();
  suffix_and_find(hist, k2, &s_bucket, &s_knew, tid);
  unsigned B2 = s_bucket, k3 = s_knew;
  __syncthreads();

  // round 3: last 10 bits
  hist[tid] = 0; hist[tid + 1024] = 0;
  __syncthreads();
  unsigned pfx = (B1 << 11) | B2;
  for (int i = tid; i < n; i += 1024) {
    unsigned u = flipf(src[i]);
    if ((u >> 10) == pfx) atomicAdd(&hist[u & 1023u], 1u);
  }
  __syncthreads();
  suffix_and_find(hist, k3, &s_bucket, &s_knew, tid);
  unsigned T = (pfx << 10) | s_bucket;

  // compact all u >= T, then bitonic sort desc by (value, ~idx)
  if (tid == 0) s_cnt = 0;
  __syncthreads();
  for (int i = tid; i < n; i += 1024) {
    unsigned u = flipf(src[i]);
    if (u >= T) {
      unsigned p = atomicAdd(&s_cnt, 1u);
      if (p < 2048u) buf[p] = ((unsigned long long)u << 32) | (unsigned long long)(~(unsigned)i);
    }
  }
  __syncthreads();
  unsigned cnt = s_cnt; if (cnt > 2048u) cnt = 2048u;
  for (int i = tid; i < 2048; i += 1024) if ((unsigned)i >= cnt) buf[i] = 0ull;
  for (unsigned kq = 2; kq <= 2048; kq <<= 1) {
    for (unsigned j = kq >> 1; j; j >>= 1) {
      __syncthreads();
      unsigned t = (unsigned)tid;
      unsigned i0 = ((t & ~(j - 1)) << 1) | (t & (j - 1));
      unsigned i1 = i0 | j;
      unsigned long long a = buf[i0], c = buf[i1];
      bool up = ((i0 & kq) == 0);
      if (up ? (a < c) : (a > c)) { buf[i0] = c; buf[i1] = a; }
    }
  }
  __syncthreads();
  if ((unsigned)tid < kk) {
    unsigned long long key = buf[tid];
    unsigned lidx = ~(unsigned)(key & 0xffffffffull);
    selAnchor[b * K_TOT + d_CAT_OFF[l] + tid] = aoff + (int)lidx;
  }
}

// ---- Kernel B: decode + clip + valid + sigmoid + sort key + per-image max coord ----
__global__ __launch_bounds__(512) void decode_kernel(
    const float* __restrict__ obj, const float* __restrict__ deltas,
    const float* __restrict__ anchors, const int* __restrict__ selAnchor,
    unsigned long long* __restrict__ skey, float4* __restrict__ boxes,
    float* __restrict__ score, float* __restrict__ maxc) {
  __shared__ float red[512];
  const int b = blockIdx.x;
  const int tid = threadIdx.x;
  float mymax = 0.0f;  // clipped coords >= 0
  for (int pos = tid; pos < K_TOT; pos += 512) {
    int a = selAnchor[b * K_TOT + pos];
    float4 an = ((const float4*)anchors)[a];
    float4 dl = ((const float4*)deltas)[(size_t)b * A_TOTAL + a];
    float o = obj[(size_t)b * A_TOTAL + a];
    float wa = fsub_(an.z, an.x), ha = fsub_(an.w, an.y);
    float cxa = fadd_(an.x, fmul_(0.5f, wa));
    float cya = fadd_(an.y, fmul_(0.5f, ha));
    const float CLIP = (float)4.135166556742356;  // log(1000/16)
    float dw = fminf(dl.z, CLIP), dh = fminf(dl.w, CLIP);
    float cx = fadd_(fmul_(dl.x, wa), cxa);
    float cy = fadd_(fmul_(dl.y, ha), cya);
    float w = fmul_((float)exp((double)dw), wa);
    float h = fmul_((float)exp((double)dh), ha);
    float x1 = fsub_(cx, fmul_(0.5f, w));
    float y1 = fsub_(cy, fmul_(0.5f, h));
    float x2 = fadd_(cx, fmul_(0.5f, w));
    float y2 = fadd_(cy, fmul_(0.5f, h));
    x1 = fminf(fmaxf(x1, 0.f), 800.f);
    y1 = fminf(fmaxf(y1, 0.f), 800.f);
    x2 = fminf(fmaxf(x2, 0.f), 800.f);
    y2 = fminf(fmaxf(y2, 0.f), 800.f);
    bool valid = (fsub_(x2, x1) >= 0.001f) && (fsub_(y2, y1) >= 0.001f);
    float s = (float)(1.0 / (1.0 + exp(-(double)o)));
    boxes[b * K_TOT + pos] = make_float4(x1, y1, x2, y2);
    score[b * K_TOT + pos] = s;
    float sm = valid ? s : -INFINITY;
    skey[b * K_TOT + pos] =
        ((unsigned long long)flipf(sm) << 32) | (unsigned long long)(~(unsigned)pos);
    mymax = fmaxf(mymax, fmaxf(fmaxf(x1, y1), fmaxf(x2, y2)));
  }
  red[tid] = mymax;
  __syncthreads();
  for (int s2 = 256; s2 > 0; s2 >>= 1) {
    if (tid < s2) red[tid] = fmaxf(red[tid], red[tid + s2]);
    __syncthreads();
  }
  if (tid == 0) maxc[b] = red[0];
}

// ---- Kernel S: stable sort by (score desc, pos asc); emit sorted arrays + valid bitmask ----
__global__ __launch_bounds__(1024) void sort_kernel(
    const unsigned long long* __restrict__ skey, const float4* __restrict__ boxes,
    const float* __restrict__ score, const float* __restrict__ maxc,
    float4* __restrict__ boxesS, float4* __restrict__ nbS,
    float* __restrict__ scoreS, unsigned long long* __restrict__ supInit) {
  __shared__ unsigned long long keys[8192];
  const int b = blockIdx.x;
  const int tid = threadIdx.x;
  for (int t = tid; t < 8192; t += 1024)
    keys[t] = (t < K_TOT) ? skey[b * K_TOT + t] : 0ull;
  for (unsigned kq = 2; kq <= 8192; kq <<= 1) {
    for (unsigned j = kq >> 1; j; j >>= 1) {
      __syncthreads();
      for (unsigned t = (unsigned)tid; t < 4096; t += 1024) {
        unsigned i0 = ((t & ~(j - 1)) << 1) | (t & (j - 1));
        unsigned i1 = i0 | j;
        unsigned long long a = keys[i0], c = keys[i1];
        bool up = ((i0 & kq) == 0);
        if (up ? (a < c) : (a > c)) { keys[i0] = c; keys[i1] = a; }
      }
    }
  }
  __syncthreads();
  float mc1 = fadd_(maxc[b], 1.0f);
  for (int t = tid; t < 8192; t += 1024) {
    unsigned long long key = keys[t];
    bool inr = t < K_TOT;
    unsigned pos = ~(unsigned)(key & 0xffffffffull);
    bool valid = inr && ((unsigned)(key >> 32) != 0x007FFFFFu);  // flip(-inf)
    if (inr) {
      float4 bx = boxes[b * K_TOT + pos];
      boxesS[b * K_TOT + t] = bx;
      int lvl = (int)(pos / 1000u);
      float offv = fmul_((float)lvl, mc1);
      nbS[b * K_TOT + t] = make_float4(fadd_(bx.x, offv), fadd_(bx.y, offv),
                                       fadd_(bx.z, offv), fadd_(bx.w, offv));
      scoreS[b * K_TOT + t] = score[b * K_TOT + pos];
    }
    unsigned long long bal = __ballot(valid);
    if (t < N_WORDS * 64 && (threadIdx.x & 63) == 0)
      supInit[b * N_WORDS + (t >> 6)] = ~bal;
  }
}

// ---- Kernel C: suppression bitmask (upper-triangular 64x64 tiles) ----
__global__ __launch_bounds__(64) void mask_kernel(const float4* __restrict__ nbS,
                                                  unsigned long long* __restrict__ mask) {
  const int b = blockIdx.y;
  int rem = blockIdx.x;
  int ib = 0;
  while (rem >= N_WORDS - ib) { rem -= (N_WORDS - ib); ++ib; }
  const int jb = ib + rem;
  __shared__ float4 jbox[64];
  __shared__ float jarea[64];
  const int lane = threadIdx.x;
  const int j0 = jb * 64;
  {
    int jj = j0 + lane;
    float4 bj = (jj < K_TOT) ? nbS[(size_t)b * K_TOT + jj]
                             : make_float4(-1e30f, -1e30f, -1e30f, -1e30f);
    jbox[lane] = bj;
    jarea[lane] = fmul_(fsub_(bj.z, bj.x), fsub_(bj.w, bj.y));
  }
  __syncthreads();
  const int i = ib * 64 + lane;
  if (i >= K_TOT) return;
  float4 bi = nbS[(size_t)b * K_TOT + i];
  float ai = fmul_(fsub_(bi.z, bi.x), fsub_(bi.w, bi.y));
  unsigned long long bits = 0ull;
  int jmax = K_TOT - j0; if (jmax > 64) jmax = 64;
  for (int q = 0; q < jmax; ++q) {
    int j = j0 + q;
    if (j <= i) continue;
    float4 bj = jbox[q];
    float ltx = fmaxf(bi.x, bj.x), lty = fmaxf(bi.y, bj.y);
    float rbx = fminf(bi.z, bj.z), rby = fminf(bi.w, bj.w);
    float wx = fmaxf(fsub_(rbx, ltx), 0.f), wy = fmaxf(fsub_(rby, lty), 0.f);
    float inter = fmul_(wx, wy);
    float uni = fsub_(fadd_(ai, jarea[q]), inter);
    float iou = inter / uni;  // IEEE div; 0/0=NaN -> not > thresh (matches ref)
    if (iou > 0.7f) bits |= (1ull << q);
  }
  mask[((size_t)b * K_TOT + i) * N_WORDS + jb] = bits;
}

// ---- Kernel D: sequential greedy-NMS scan, one wave per image ----
// R10 post-mortem: even guaranteed-clustered asm loads = 174us => load issue
// order was never the bottleneck. Real profile (random data, sparse
// suppression): ~55-60 kept/word, early exit at w~17; cost/word = 4 serial
// 16-row OR batches + serial 60-iter emit. R11 design:
//  * prefetch ALL avail rows (<=64, kept is a subset) col=lane via volatile
//    asm BEFORE the serial scan -> one latency/word, hidden under the scan.
//  * parallel ballot/popcount emit (was a 60-iter serial loop).
//  * only words 0..63 (supA) ORed incrementally; supB (words 64-70) is
//    reconstructed from keptIdx at w==64 (cold path: early exit at w~17
//    means it never runs on this data, but it is correct if reached).
__global__ __launch_bounds__(64, 1) void scan_kernel(
    const unsigned long long* __restrict__ mask,
    const unsigned long long* __restrict__ supInit,
    const float4* __restrict__ boxesS, const float* __restrict__ scoreS,
    float* __restrict__ out) {
  __shared__ unsigned short keptIdx[POST_N];
  const int b = blockIdx.x;
  const int lane = threadIdx.x;
  const unsigned long long* m = mask + (size_t)b * K_TOT * N_WORDS;
  unsigned long long supA = supInit[b * N_WORDS + lane];                       // word = lane
  unsigned long long supB = (lane < N_WORDS - 64) ? supInit[b * N_WORDS + 64 + lane] : ~0ull;
  float4* ob = (float4*)(out + (size_t)b * POST_N * 4);
  float* os = out + 4 * POST_N * 4 + (size_t)b * POST_N;
  const int lane2 = (lane + 64 < N_WORDS) ? (lane + 64) : lane;  // clamped 2nd column
  int c = 0;
  unsigned long long rw_cur = (lane < K_TOT) ? m[(size_t)lane * N_WORDS] : 0ull;
  for (int w = 0; w < N_WORDS; ++w) {
    // prefetch next group's diagonal word
    unsigned long long rw_next = 0ull;
    if (w + 1 < N_WORDS) {
      int i1 = (w + 1) * 64 + lane;
      if (i1 < K_TOT) rw_next = m[(size_t)i1 * N_WORDS + (w + 1)];
    }
    // lazy supB: fold all kept-so-far rows' cols 64..70 in, once (cold path)
    if (w == 64) {
      for (int j = 0; j < N_WORDS - 64; ++j) {
        unsigned long long acc = 0ull;
        for (int base = 0; base < c; base += 64) {
          int k2 = base + lane;
          unsigned long long v2 = 0ull;
          if (k2 < c) v2 = m[(size_t)keptIdx[k2] * N_WORDS + 64 + j];
          acc |= v2;
        }
        for (int msk = 32; msk > 0; msk >>= 1) acc |= shflxor64(acc, msk);
        if (lane == j) supB |= acc;
      }
    }
    unsigned long long v = (w < 64) ? supA : supB;
    int srcl = (w < 64) ? w : (w - 64);
    unsigned long long scur = readlane64(v, srcl);
    unsigned long long avail0 = ~scur;
    unsigned long long keptm = 0ull;

    if (w < 64) {
      // ---- fast path: prefetch ALL avail rows (col = lane) ----
      int tq[64];
      unsigned long long dA[64];
      unsigned long long av = avail0;
      if (avail0) {
#pragma unroll
        for (int q = 0; q < 64; ++q) {
          unsigned long long avq = av ? av : 1ull;       // cndmask, no branch
          tq[q] = __builtin_ctzll(avq);
          av &= av - 1ull;
          const unsigned long long* rp = m + (size_t)(w * 64 + tq[q]) * N_WORDS;
          asm volatile("global_load_dwordx2 %0, %1, off" : "=&v"(dA[q]) : "v"(rp + lane));
        }
      }
      __builtin_amdgcn_sched_barrier(0);
      // serial within-word greedy scan (overlaps the in-flight loads)
      unsigned long long avail = avail0;
      while (avail) {
        int t = __builtin_ctzll(avail);
        keptm |= (1ull << t);
        unsigned long long rw = readlane64(rw_cur, t);
        avail &= ~(rw | (1ull << t));
      }
      // parallel emit (ballot-style): rank = popcount of lower kept bits
      int nk = __popcll(keptm);
      if (keptm) {
        int pos = c + (int)__popcll(keptm & ((1ull << lane) - 1ull));
        if (((keptm >> lane) & 1ull) && pos < POST_N)
          keptIdx[pos] = (unsigned short)(w * 64 + lane);
      }
      c += nk;
      if (c >= POST_N) break;
      // drain + masked OR into supA (rule 18: sched_barrier after waitcnt)
      if (avail0) {
        asm volatile("s_waitcnt vmcnt(0)" ::: "memory");
        __builtin_amdgcn_sched_barrier(0);
        unsigned long long acc0 = 0ull;
#pragma unroll
        for (int q = 0; q < 64; ++q) {
          unsigned long long sel = ((keptm >> tq[q]) & 1ull) ? ~0ull : 0ull;
          acc0 |= dA[q] & sel;
        }
        supA |= acc0;
      }
    } else {
      // ---- tail path (w in [64,70]): original serial scan + 16-row batches
      unsigned long long avail = avail0;
      while (avail) {
        int t = __builtin_ctzll(avail);
        keptm |= (1ull << t);
        unsigned long long rw = readlane64(rw_cur, t);
        avail &= ~(rw | (1ull << t));
      }
      int nk = __popcll(keptm);
      if (keptm) {
        int pos = c + (int)__popcll(keptm & ((1ull << lane) - 1ull));
        if (((keptm >> lane) & 1ull) && pos < POST_N)
          keptIdx[pos] = (unsigned short)(w * 64 + lane);
      }
      c += nk;
      if (c >= POST_N) break;
      if (w + 1 >= N_WORDS) break;
      unsigned long long km = keptm;
      while (km != 0ull) {
        int ts[16];
        unsigned long long vm[16];
#pragma unroll
        for (int q = 0; q < 16; ++q) {
          unsigned long long kms = km ? km : 1ull;
          ts[q] = __builtin_ctzll(kms);
          vm[q] = km ? ~0ull : 0ull;
          km &= km - 1ull;
        }
        unsigned long long dA2[16], dB2[16];
#pragma unroll
        for (int q = 0; q < 16; ++q) {
          const unsigned long long* row = m + (size_t)(w * 64 + ts[q]) * N_WORDS;
          dA2[q] = row[lane];
          dB2[q] = row[lane2];
        }
        __builtin_amdgcn_sched_barrier(0);
        unsigned long long acc0 = 0ull, acc1 = 0ull;
#pragma unroll
        for (int q = 0; q < 16; ++q) {
          acc0 |= dA2[q] & vm[q];
          acc1 |= dB2[q] & vm[q];
        }
        supA |= acc0; supB |= acc1;
      }
    }
    rw_cur = rw_next;
  }
  __syncthreads();  // make LDS keptIdx writes visible to all lanes
  // parallel gather+store of the kept boxes (64 lanes, independent loads)
  for (int t2 = lane; t2 < c && t2 < POST_N; t2 += 64) {
    int i = keptIdx[t2];
    ob[t2] = boxesS[(size_t)b * K_TOT + i];
    os[t2] = scoreS[(size_t)b * K_TOT + i];
  }
  // zero-pad remaining output slots (out is poisoned each launch)
  for (int t2 = (c < POST_N ? c : POST_N) + lane; t2 < POST_N; t2 += 64) {
    ob[t2] = make_float4(0.f, 0.f, 0.f, 0.f);
    os[t2] = 0.f;
  }
}

extern "C" void kernel_launch(void* const* d_in, const int* in_sizes, int n_in,
                              void* d_out, int out_size, void* d_ws, size_t ws_size,
                              hipStream_t stream) {
  const float* obj = (const float*)d_in[0];
  const float* deltas = (const float*)d_in[1];
  const float* anchors = (const float*)d_in[2];
  float* out = (float*)d_out;
  char* ws = (char*)d_ws;

  int* selAnchor = (int*)(ws + OFF_SEL);
  unsigned long long* skey = (unsigned long long*)(ws + OFF_SKEY);
  float4* boxes = (float4*)(ws + OFF_BOXES);
  float* score = (float*)(ws + OFF_SCORE);
  float* maxc = (float*)(ws + OFF_MAXC);
  float4* boxesS = (float4*)(ws + OFF_BOXESS);
  float4* nbS = (float4*)(ws + OFF_NBS);
  float* scoreS = (float*)(ws + OFF_SCORES);
  unsigned long long* supInit = (unsigned long long*)(ws + OFF_SUPINIT);
  unsigned long long* mask = (unsigned long long*)(ws + OFF_MASK);

  hipLaunchKernelGGL(topk_kernel, dim3(BATCH * 5), dim3(1024), 0, stream, obj, selAnchor);
  hipLaunchKernelGGL(decode_kernel, dim3(BATCH), dim3(512), 0, stream,
                     obj, deltas, anchors, selAnchor, skey, boxes, score, maxc);
  hipLaunchKernelGGL(sort_kernel, dim3(BATCH), dim3(1024), 0, stream,
                     skey, boxes, score, maxc, boxesS, nbS, scoreS, supInit);
  hipLaunchKernelGGL(mask_kernel, dim3(N_WORDS * (N_WORDS + 1) / 2, BATCH), dim3(64), 0, stream,
                     nbS, mask);
  hipLaunchKernelGGL(scan_kernel, dim3(BATCH), dim3(64), 0, stream,
                     mask, supInit, boxesS, scoreS, out);
}